// Round 1
// baseline (12258.740 us; speedup 1.0000x reference)
//
#include <hip/hip_runtime.h>
#include <math.h>

// Problem constants: B=4, CIN=128, COUT=256, H=W=384, K=3
// Phases: k = kh*3+kw (h%3, w%3); L = (384/3)^2 = 16384 patches.
// y chunk layout (per q=(b,kh)): y[qL][ch 0..383][kw 0..2][l 0..16383]
//   ch 0..127  = conv(x,w1) channels (y1)
//   ch 128..383= conv(x,w2) channels (y2)

static __device__ __forceinline__ float wave_max(float v) {
    #pragma unroll
    for (int off = 32; off > 0; off >>= 1)
        v = fmaxf(v, __shfl_xor(v, off, 64));
    return v;
}
static __device__ __forceinline__ float wave_sum(float v) {
    #pragma unroll
    for (int off = 32; off > 0; off >>= 1)
        v += __shfl_xor(v, off, 64);
    return v;
}

// grid (384 = 3 wtiles * 128 ph, 3 ch-blocks of 128, nq), block 256.
// Each thread: 16 ch x 4 px (px strided by 32 within a 128-wide row tile).
__global__ __launch_bounds__(256)
void conv_phase(const float* __restrict__ x,
                const float* __restrict__ w1,
                const float* __restrict__ w2,
                float* __restrict__ y,
                int q0)
{
    const int tid = threadIdx.x;
    const int wt  = blockIdx.x % 3;
    const int ph  = blockIdx.x / 3;
    const int qL  = blockIdx.z;
    const int q   = q0 + qL;
    const int b   = q / 3;
    const int kh  = q % 3;
    const int h   = 3 * ph + kh;
    const int ch0 = blockIdx.y * 128;
    const int pxt = tid & 31;
    const int cg  = tid >> 5;           // 8 groups of 16 channels
    const int wbase = wt * 128 + pxt;   // + 32*j, j=0..3

    const float* xb = x + (size_t)b * 128 * 384 * 384;

    __shared__ float wlds[144][128];    // [ciL*9+j][chL]  73728 B

    float acc[4][16];
    #pragma unroll
    for (int j = 0; j < 4; ++j)
        #pragma unroll
        for (int c = 0; c < 16; ++c) acc[j][c] = 0.f;

    // weight staging assignment: 2 threads per channel, 72 consecutive j each
    const int chL = tid >> 1;
    const int jh  = (tid & 1) * 72;
    const int chg = ch0 + chL;
    const float* wsrc = (chg < 128) ? (w1 + (size_t)chg * 1152)
                                    : (w2 + (size_t)(chg - 128) * 1152);

    for (int cc = 0; cc < 128; cc += 16) {
        __syncthreads();
        const float* src = wsrc + cc * 9 + jh;   // contiguous j = (cc..cc+15)x9
        #pragma unroll
        for (int s = 0; s < 72; s += 4) {
            float4 v = *(const float4*)(src + s);
            wlds[jh + s + 0][chL] = v.x;
            wlds[jh + s + 1][chL] = v.y;
            wlds[jh + s + 2][chL] = v.z;
            wlds[jh + s + 3][chL] = v.w;
        }
        __syncthreads();

        #pragma unroll 1
        for (int ciL = 0; ciL < 16; ++ciL) {
            const float* xc = xb + (size_t)(cc + ciL) * 384 * 384;
            #pragma unroll
            for (int dy = 0; dy < 3; ++dy) {
                const int hh = h + dy - 1;
                const bool hv = (unsigned)hh < 384u;
                const float* xr = xc + hh * 384;
                #pragma unroll
                for (int dx = 0; dx < 3; ++dx) {
                    const int jf = ciL * 9 + dy * 3 + dx;
                    float wv[16];
                    *(float4*)&wv[0]  = *(const float4*)&wlds[jf][cg * 16 + 0];
                    *(float4*)&wv[4]  = *(const float4*)&wlds[jf][cg * 16 + 4];
                    *(float4*)&wv[8]  = *(const float4*)&wlds[jf][cg * 16 + 8];
                    *(float4*)&wv[12] = *(const float4*)&wlds[jf][cg * 16 + 12];
                    float xv[4];
                    #pragma unroll
                    for (int j = 0; j < 4; ++j) {
                        const int wwp = wbase + 32 * j + dx - 1;
                        xv[j] = (hv && (unsigned)wwp < 384u) ? xr[wwp] : 0.f;
                    }
                    #pragma unroll
                    for (int j = 0; j < 4; ++j)
                        #pragma unroll
                        for (int c = 0; c < 16; ++c)
                            acc[j][c] = fmaf(xv[j], wv[c], acc[j][c]);
                }
            }
        }
    }

    // write phase-separated output
    #pragma unroll
    for (int j = 0; j < 4; ++j) {
        const int wp = wbase + 32 * j;
        const int kw = wp % 3;
        const int pw = wp / 3;
        const int l  = ph * 128 + pw;
        #pragma unroll
        for (int c = 0; c < 16; ++c) {
            const int ch = ch0 + cg * 16 + c;
            y[((size_t)qL * 384 + ch) * 3 * 16384 + (size_t)kw * 16384 + l] = acc[j][c];
        }
    }
}

// grid (NS lsplit, 12 = kw*4+otile, nq), block 256.
// Block tile: 64 o x 128 i; thread 8o x 4i. Partial sums atomicAdd'ed to out.
__global__ __launch_bounds__(256)
void corr_phase(const float* __restrict__ y,
                float* __restrict__ out,
                int q0, int lchunk)
{
    const int tid = threadIdx.x;
    const int qL  = blockIdx.z;
    const int q   = q0 + qL;
    const int b   = q / 3;
    const int kh  = q % 3;
    const int kw  = blockIdx.y >> 2;
    const int ot  = blockIdx.y & 3;
    const int l0  = blockIdx.x * lchunk;
    const int othr = tid >> 5;   // 0..7
    const int ithr = tid & 31;   // 0..31

    const float* y1 = y + (size_t)qL * 384 * 3 * 16384 + (size_t)kw * 16384;
    const float* y2 = y1 + (size_t)(128 + ot * 64) * 3 * 16384;

    __shared__ float s2[32][68];    // [lL][o]  (pad 68: 16B-aligned rows, low conflict)
    __shared__ float s1[32][132];   // [lL][i]

    float acc[8][4];
    #pragma unroll
    for (int oc = 0; oc < 8; ++oc)
        #pragma unroll
        for (int ic = 0; ic < 4; ++ic) acc[oc][ic] = 0.f;

    for (int lb = l0; lb < l0 + lchunk; lb += 32) {
        __syncthreads();
        #pragma unroll
        for (int p = 0; p < 8; ++p) {
            const int o = p * 8 + othr;
            s2[ithr][o] = y2[(size_t)o * 3 * 16384 + lb + ithr];
        }
        #pragma unroll
        for (int p = 0; p < 16; ++p) {
            const int i = p * 8 + othr;
            s1[ithr][i] = y1[(size_t)i * 3 * 16384 + lb + ithr];
        }
        __syncthreads();
        #pragma unroll
        for (int lL = 0; lL < 32; ++lL) {
            float ov[8], iv[4];
            *(float4*)&ov[0] = *(const float4*)&s2[lL][othr * 8 + 0];
            *(float4*)&ov[4] = *(const float4*)&s2[lL][othr * 8 + 4];
            *(float4*)&iv[0] = *(const float4*)&s1[lL][ithr * 4];
            #pragma unroll
            for (int oc = 0; oc < 8; ++oc)
                #pragma unroll
                for (int ic = 0; ic < 4; ++ic)
                    acc[oc][ic] = fmaf(ov[oc], iv[ic], acc[oc][ic]);
        }
    }

    const int kk = kh * 3 + kw;
    #pragma unroll
    for (int oc = 0; oc < 8; ++oc) {
        const int o = ot * 64 + othr * 8 + oc;
        #pragma unroll
        for (int ic = 0; ic < 4; ++ic) {
            const int i = ithr * 4 + ic;
            atomicAdd(&out[((size_t)(b * 256 + o) * 128 + i) * 9 + kk], acc[oc][ic]);
        }
    }
}

// In-place softmax over rows of 1152 (row = b*256+o), with 1/sqrt(1152) scale.
__global__ __launch_bounds__(256)
void softmax_rows(float* __restrict__ out)
{
    const int r = blockIdx.x;
    float* p = out + (size_t)r * 1152;
    const int tid = threadIdx.x;
    const float scale = 0.029462782549439476f;  // 1/sqrt(128*9)

    float v[5];
    float m = -3.0e38f;
    #pragma unroll
    for (int k = 0; k < 4; ++k) {
        v[k] = p[tid + k * 256] * scale;
        m = fmaxf(m, v[k]);
    }
    const bool t5 = tid < 128;
    v[4] = t5 ? p[tid + 1024] * scale : -3.0e38f;
    m = fmaxf(m, v[4]);

    m = wave_max(m);
    __shared__ float red[4];
    const int wid = tid >> 6, lane = tid & 63;
    if (lane == 0) red[wid] = m;
    __syncthreads();
    m = fmaxf(fmaxf(red[0], red[1]), fmaxf(red[2], red[3]));

    float s = 0.f;
    #pragma unroll
    for (int k = 0; k < 4; ++k) { v[k] = __expf(v[k] - m); s += v[k]; }
    v[4] = t5 ? __expf(v[4] - m) : 0.f;
    s += v[4];

    s = wave_sum(s);
    __syncthreads();
    if (lane == 0) red[wid] = s;
    __syncthreads();
    s = red[0] + red[1] + red[2] + red[3];
    const float inv = 1.0f / s;
    #pragma unroll
    for (int k = 0; k < 4; ++k) p[tid + k * 256] = v[k] * inv;
    if (t5) p[tid + 1024] = v[4] * inv;
}

extern "C" void kernel_launch(void* const* d_in, const int* in_sizes, int n_in,
                              void* d_out, int out_size, void* d_ws, size_t ws_size,
                              hipStream_t stream)
{
    const float* x  = (const float*)d_in[0];   // [4][128][384][384]
    const float* w1 = (const float*)d_in[1];   // [128][128][3][3]
    const float* w2 = (const float*)d_in[2];   // [256][128][3][3]
    float* out = (float*)d_out;                // [4][256][128][9] fp32
    float* y   = (float*)d_ws;

    const size_t chunk_bytes = (size_t)384 * 3 * 16384 * sizeof(float); // 75.5 MB per (b,kh)
    int nq, NS;
    if (ws_size >= 12 * chunk_bytes)      { nq = 12; NS = 8;  }  // all at once
    else if (ws_size >= 3 * chunk_bytes)  { nq = 3;  NS = 32; }  // per batch
    else                                  { nq = 1;  NS = 64; }  // per (b,kh)
    const int lchunk = 16384 / NS;

    hipMemsetAsync(d_out, 0, (size_t)out_size * sizeof(float), stream);

    for (int q0 = 0; q0 < 12; q0 += nq) {
        dim3 cgrid(384, 3, nq);
        conv_phase<<<cgrid, 256, 0, stream>>>(x, w1, w2, y, q0);
        dim3 rgrid(NS, 12, nq);
        corr_phase<<<rgrid, 256, 0, stream>>>(y, out, q0, lchunk);
    }
    softmax_rows<<<1024, 256, 0, stream>>>(out);
}

// Round 2
// 3066.154 us; speedup vs baseline: 3.9981x; 3.9981x over previous
//
#include <hip/hip_runtime.h>
#include <math.h>

typedef __attribute__((ext_vector_type(8))) short short8;
typedef __attribute__((ext_vector_type(4))) float floatx4;

#define XT_H 386  // 384 + 2 halo

// ---------- helpers ----------
static __device__ __forceinline__ unsigned short f2bf(float f) {
    unsigned u = __float_as_uint(f);
    u += 0x7fffu + ((u >> 16) & 1u);        // round-to-nearest-even
    return (unsigned short)(u >> 16);
}
static __device__ __forceinline__ float bf2f(unsigned short h) {
    return __uint_as_float(((unsigned)h) << 16);
}
static __device__ __forceinline__ void async16(const void* g, void* l) {
    __builtin_amdgcn_global_load_lds(
        (const __attribute__((address_space(1))) void*)g,
        (__attribute__((address_space(3))) void*)l, 16, 0, 0);
}
static __device__ __forceinline__ float wave_max(float v) {
    #pragma unroll
    for (int off = 32; off > 0; off >>= 1) v = fmaxf(v, __shfl_xor(v, off, 64));
    return v;
}
static __device__ __forceinline__ float wave_sum(float v) {
    #pragma unroll
    for (int off = 32; off > 0; off >>= 1) v += __shfl_xor(v, off, 64);
    return v;
}

// ---------- A build: w -> A[ch 384][tap*128+ci] bf16 hi/lo ----------
__global__ __launch_bounds__(256)
void build_A(const float* __restrict__ w1, const float* __restrict__ w2,
             unsigned short* __restrict__ A_hi, unsigned short* __restrict__ A_lo)
{
    int idx = blockIdx.x * 256 + threadIdx.x;
    if (idx >= 384 * 1152) return;
    int ch  = idx / 1152;
    int rem = idx - ch * 1152;
    int tap = rem >> 7;
    int ci  = rem & 127;
    float v = (ch < 128) ? w1[ch * 1152 + ci * 9 + tap]
                         : w2[(size_t)(ch - 128) * 1152 + ci * 9 + tap];
    unsigned short hi = f2bf(v);
    unsigned short lo = f2bf(v - bf2f(hi));
    A_hi[idx] = hi;
    A_lo[idx] = lo;
}

// ---------- transpose+split: x[b][ci][h][w] -> xt_{hi,lo}[bl][h+1][w+1][ci] ----------
__global__ __launch_bounds__(256)
void transpose_split(const float* __restrict__ x,
                     unsigned short* __restrict__ xt_hi,
                     unsigned short* __restrict__ xt_lo,
                     int b0)
{
    __shared__ unsigned short sh[2][64][136];  // padded row: spreads readback banks
    const int t  = threadIdx.x;
    const int w0 = blockIdx.x * 64;
    const int h  = blockIdx.y;
    const int bl = blockIdx.z;
    const int b  = b0 + bl;
    {
        const int ci = t >> 1;
        const int ws = (t & 1) * 32;
        const float* src = x + (((size_t)(b * 128 + ci) * 384 + h) * 384 + w0 + ws);
        #pragma unroll
        for (int j = 0; j < 8; ++j) {
            float4 v = *(const float4*)(src + j * 4);
            float vv[4] = {v.x, v.y, v.z, v.w};
            #pragma unroll
            for (int e = 0; e < 4; ++e) {
                unsigned short hi = f2bf(vv[e]);
                unsigned short lo = f2bf(vv[e] - bf2f(hi));
                sh[0][ws + j * 4 + e][ci] = hi;
                sh[1][ws + j * 4 + e][ci] = lo;
            }
        }
    }
    __syncthreads();
    const int wl = t >> 2;
    const int cs = (t & 3) * 32;
    size_t dst = (((size_t)bl * XT_H + (h + 1)) * XT_H + (w0 + wl + 1)) * 128 + cs;
    #pragma unroll
    for (int j = 0; j < 4; ++j) {
        *(uint4*)(xt_hi + dst + j * 8) = *(const uint4*)(&sh[0][wl][cs + j * 8]);
        *(uint4*)(xt_lo + dst + j * 8) = *(const uint4*)(&sh[1][wl][cs + j * 8]);
    }
}

// ---------- conv: implicit GEMM, 128ch x 128px tiles, bf16x3 split MFMA ----------
// grid (3 Mtile, 1152 = h*3+kw, nb); block 256 (4 waves, each 64x64)
__global__ __launch_bounds__(256)
void conv_mfma(const unsigned short* __restrict__ A_hi,
               const unsigned short* __restrict__ A_lo,
               const unsigned short* __restrict__ xt_hi,
               const unsigned short* __restrict__ xt_lo,
               unsigned short* __restrict__ y_hi,
               unsigned short* __restrict__ y_lo)
{
    __shared__ __align__(16) char smem[32768];
    char* sAh = smem;
    char* sAl = smem + 8192;
    char* sBh = smem + 16384;
    char* sBl = smem + 24576;

    const int t    = threadIdx.x;
    const int lane = t & 63;
    const int wave = t >> 6;
    const int wm   = wave & 1, wn = wave >> 1;

    const int mt  = blockIdx.x;
    const int hkw = blockIdx.y;
    const int h   = hkw / 3;
    const int kw  = hkw - 3 * h;
    const int bl  = blockIdx.z;
    const int ch0 = mt * 128;
    const int ph  = h / 3;
    const int kh  = h - 3 * ph;

    // A staging: thread -> (row chL, buf)
    const int chL  = t & 127;
    const int abuf = t >> 7;
    const unsigned short* Abase = (abuf ? A_lo : A_hi) + (size_t)(ch0 + chL) * 1152;
    char* sA = (abuf ? sAl : sAh) + chL * 64;
    const int aswz = (chL >> 1) & 3;

    floatx4 acc[4][4];
    #pragma unroll
    for (int i = 0; i < 4; ++i)
        #pragma unroll
        for (int j = 0; j < 4; ++j) acc[i][j] = (floatx4){0.f, 0.f, 0.f, 0.f};

    const size_t xt_b = (size_t)bl * XT_H * XT_H * 128;

    // frag-read offsets (constant across K-steps)
    const int ml  = lane & 15, ko = lane >> 4;
    const int chb = wm * 64 + ml;
    const int aoff = chb * 64 + ((ko ^ ((chb >> 1) & 3)) << 4);
    const int pxb = wn * 64 + ml;
    const int boff = pxb * 64 + ((ko ^ ((pxb >> 1) & 3)) << 4);

    #pragma unroll 1
    for (int s = 0; s < 36; ++s) {
        const int tap = s >> 2;
        const int ci0 = (s & 3) << 5;
        const int dy  = tap / 3;
        const int dx  = tap - 3 * dy;

        __syncthreads();
        // stage A (128x32 x2 bufs) via ds_write_b128, XOR-swizzled groups
        {
            const unsigned short* ag = Abase + tap * 128 + ci0;
            uint4 v0 = *(const uint4*)(ag);
            uint4 v1 = *(const uint4*)(ag + 8);
            uint4 v2 = *(const uint4*)(ag + 16);
            uint4 v3 = *(const uint4*)(ag + 24);
            *(uint4*)(sA + ((0 ^ aswz) << 4)) = v0;
            *(uint4*)(sA + ((1 ^ aswz) << 4)) = v1;
            *(uint4*)(sA + ((2 ^ aswz) << 4)) = v2;
            *(uint4*)(sA + ((3 ^ aswz) << 4)) = v3;
        }
        // stage B (128px x 32ci x2 bufs) via global_load_lds width=16 (no masking: halo)
        {
            const size_t rowb = xt_b + (size_t)(h + dy) * XT_H * 128;
            #pragma unroll
            for (int is = 0; is < 2; ++is) {
                const int slot = wave * 128 + is * 64 + lane;
                const int px = slot >> 2;
                const int gp = slot & 3;
                const int g  = gp ^ ((px >> 1) & 3);
                const size_t go = rowb + (size_t)(kw + 3 * px + dx) * 128 + ci0 + g * 8;
                char* dh = sBh + wave * 2048 + is * 1024;
                char* dl = sBl + wave * 2048 + is * 1024;
                async16(xt_hi + go, dh);
                async16(xt_lo + go, dl);
            }
        }
        __syncthreads();

        short8 Ah[4], Al[4];
        #pragma unroll
        for (int fm = 0; fm < 4; ++fm) {
            Ah[fm] = *(const short8*)(sAh + aoff + fm * 1024);
            Al[fm] = *(const short8*)(sAl + aoff + fm * 1024);
        }
        #pragma unroll
        for (int fn = 0; fn < 4; ++fn) {
            short8 Bh = *(const short8*)(sBh + boff + fn * 1024);
            short8 Bl = *(const short8*)(sBl + boff + fn * 1024);
            #pragma unroll
            for (int fm = 0; fm < 4; ++fm) {
                acc[fm][fn] = __builtin_amdgcn_mfma_f32_16x16x32_bf16(Ah[fm], Bh, acc[fm][fn], 0, 0, 0);
                acc[fm][fn] = __builtin_amdgcn_mfma_f32_16x16x32_bf16(Ah[fm], Bl, acc[fm][fn], 0, 0, 0);
                acc[fm][fn] = __builtin_amdgcn_mfma_f32_16x16x32_bf16(Al[fm], Bh, acc[fm][fn], 0, 0, 0);
            }
        }
    }

    // epilogue: split to bf16 hi/lo, phase-separated y[bl][ch][kh*3+kw][ph*128+pw]
    const int qd  = lane >> 4;
    const int kk9 = kh * 3 + kw;
    #pragma unroll
    for (int fm = 0; fm < 4; ++fm) {
        #pragma unroll
        for (int r = 0; r < 4; ++r) {
            const int chl = wm * 64 + fm * 16 + qd * 4 + r;
            const size_t rowo = (((size_t)bl * 384 + ch0 + chl) * 9 + kk9) * 16384 + (size_t)ph * 128;
            #pragma unroll
            for (int fn = 0; fn < 4; ++fn) {
                const int pw = wn * 64 + fn * 16 + ml;
                float v = acc[fm][fn][r];
                unsigned short hi = f2bf(v);
                unsigned short lo = f2bf(v - bf2f(hi));
                y_hi[rowo + pw] = hi;
                y_lo[rowo + pw] = lo;
            }
        }
    }
}

// ---------- corr: C[o 128][i 128] per (b, phase, mt), K-split x8, atomics ----------
// grid (8 ksplit, 18 = phase*2+mt, nb); block 256
__global__ __launch_bounds__(256)
void corr_mfma(const unsigned short* __restrict__ y_hi,
               const unsigned short* __restrict__ y_lo,
               float* __restrict__ out, int b0)
{
    __shared__ __align__(16) char smem[32768];
    char* sAh = smem;
    char* sAl = smem + 8192;
    char* sBh = smem + 16384;
    char* sBl = smem + 24576;

    const int t = threadIdx.x, lane = t & 63, wave = t >> 6;
    const int wm = wave & 1, wn = wave >> 1;
    const int ks = blockIdx.x;
    const int phase = blockIdx.y >> 1;
    const int mt = blockIdx.y & 1;
    const int bl = blockIdx.z;
    const int b  = b0 + bl;

    const size_t CHS = (size_t)9 * 16384;  // y channel stride (elements)
    const size_t y1b = (size_t)(bl * 384) * CHS + (size_t)phase * 16384;
    const size_t y2b = (size_t)(bl * 384 + 128 + mt * 128) * CHS + (size_t)phase * 16384;

    floatx4 acc[4][4];
    #pragma unroll
    for (int i = 0; i < 4; ++i)
        #pragma unroll
        for (int j = 0; j < 4; ++j) acc[i][j] = (floatx4){0.f, 0.f, 0.f, 0.f};

    const int ml = lane & 15, ko = lane >> 4;
    const int ob = wm * 64 + ml;
    const int aoff = ob * 64 + ((ko ^ ((ob >> 1) & 3)) << 4);
    const int ib = wn * 64 + ml;
    const int boff = ib * 64 + ((ko ^ ((ib >> 1) & 3)) << 4);

    #pragma unroll 1
    for (int st = 0; st < 64; ++st) {
        const int l0 = ks * 2048 + st * 32;
        __syncthreads();
        #pragma unroll
        for (int is = 0; is < 2; ++is) {
            const int slot = wave * 128 + is * 64 + lane;
            const int row = slot >> 2;
            const int gp  = slot & 3;
            const int g   = gp ^ ((row >> 1) & 3);
            const size_t o2 = y2b + (size_t)row * CHS + l0 + g * 8;
            const size_t o1 = y1b + (size_t)row * CHS + l0 + g * 8;
            char* base = smem + wave * 2048 + is * 1024;
            async16(y_hi + o2, base);            // sAh
            async16(y_lo + o2, base + 8192);     // sAl
            async16(y_hi + o1, base + 16384);    // sBh
            async16(y_lo + o1, base + 24576);    // sBl
        }
        __syncthreads();

        short8 Ah[4], Al[4];
        #pragma unroll
        for (int fm = 0; fm < 4; ++fm) {
            Ah[fm] = *(const short8*)(sAh + aoff + fm * 1024);
            Al[fm] = *(const short8*)(sAl + aoff + fm * 1024);
        }
        #pragma unroll
        for (int fn = 0; fn < 4; ++fn) {
            short8 Bh = *(const short8*)(sBh + boff + fn * 1024);
            short8 Bl = *(const short8*)(sBl + boff + fn * 1024);
            #pragma unroll
            for (int fm = 0; fm < 4; ++fm) {
                acc[fm][fn] = __builtin_amdgcn_mfma_f32_16x16x32_bf16(Ah[fm], Bh, acc[fm][fn], 0, 0, 0);
                acc[fm][fn] = __builtin_amdgcn_mfma_f32_16x16x32_bf16(Ah[fm], Bl, acc[fm][fn], 0, 0, 0);
                acc[fm][fn] = __builtin_amdgcn_mfma_f32_16x16x32_bf16(Al[fm], Bh, acc[fm][fn], 0, 0, 0);
            }
        }
    }

    const int qd = lane >> 4;
    #pragma unroll
    for (int fm = 0; fm < 4; ++fm) {
        #pragma unroll
        for (int r = 0; r < 4; ++r) {
            const int o = mt * 128 + wm * 64 + fm * 16 + qd * 4 + r;
            #pragma unroll
            for (int fn = 0; fn < 4; ++fn) {
                const int i = wn * 64 + fn * 16 + ml;
                atomicAdd(&out[((size_t)(b * 256 + o) * 128 + i) * 9 + phase],
                          acc[fm][fn][r]);
            }
        }
    }
}

// ---------- softmax over rows of 1152, scale 1/sqrt(1152) ----------
__global__ __launch_bounds__(256)
void softmax_rows(float* __restrict__ out)
{
    const int r = blockIdx.x;
    float* p = out + (size_t)r * 1152;
    const int tid = threadIdx.x;
    const float scale = 0.029462782549439476f;

    float v[5];
    float m = -3.0e38f;
    #pragma unroll
    for (int k = 0; k < 4; ++k) {
        v[k] = p[tid + k * 256] * scale;
        m = fmaxf(m, v[k]);
    }
    const bool t5 = tid < 128;
    v[4] = t5 ? p[tid + 1024] * scale : -3.0e38f;
    m = fmaxf(m, v[4]);

    m = wave_max(m);
    __shared__ float red[4];
    const int wid = tid >> 6, lane = tid & 63;
    if (lane == 0) red[wid] = m;
    __syncthreads();
    m = fmaxf(fmaxf(red[0], red[1]), fmaxf(red[2], red[3]));

    float s = 0.f;
    #pragma unroll
    for (int k = 0; k < 4; ++k) { v[k] = __expf(v[k] - m); s += v[k]; }
    v[4] = t5 ? __expf(v[4] - m) : 0.f;
    s += v[4];

    s = wave_sum(s);
    __syncthreads();
    if (lane == 0) red[wid] = s;
    __syncthreads();
    s = red[0] + red[1] + red[2] + red[3];
    const float inv = 1.0f / s;
    #pragma unroll
    for (int k = 0; k < 4; ++k) p[tid + k * 256] = v[k] * inv;
    if (t5) p[tid + 1024] = v[4] * inv;
}

// ---------- launch ----------
extern "C" void kernel_launch(void* const* d_in, const int* in_sizes, int n_in,
                              void* d_out, int out_size, void* d_ws, size_t ws_size,
                              hipStream_t stream)
{
    const float* x  = (const float*)d_in[0];
    const float* w1 = (const float*)d_in[1];
    const float* w2 = (const float*)d_in[2];
    float* out = (float*)d_out;

    const size_t A_BYTES = (size_t)384 * 1152 * 2;            // 884736 per buf
    auto need = [&](int nb) {
        size_t xt = (size_t)nb * XT_H * XT_H * 128 * 2;       // per buf
        size_t yb = (size_t)nb * 384 * 9 * 16384 * 2;         // per buf
        return 2 * A_BYTES + 2 * xt + 2 * yb;
    };
    int nb = (ws_size >= need(4)) ? 4 : 1;

    const size_t xtb = (size_t)nb * XT_H * XT_H * 128 * 2;
    const size_t yb  = (size_t)nb * 384 * 9 * 16384 * 2;

    char* ws = (char*)d_ws;
    unsigned short* A_hi  = (unsigned short*)(ws);
    unsigned short* A_lo  = (unsigned short*)(ws + A_BYTES);
    unsigned short* xt_hi = (unsigned short*)(ws + 2 * A_BYTES);
    unsigned short* xt_lo = (unsigned short*)(ws + 2 * A_BYTES + xtb);
    unsigned short* y_hi  = (unsigned short*)(ws + 2 * A_BYTES + 2 * xtb);
    unsigned short* y_lo  = (unsigned short*)(ws + 2 * A_BYTES + 2 * xtb + yb);

    build_A<<<1728, 256, 0, stream>>>(w1, w2, A_hi, A_lo);
    hipMemsetAsync(d_out, 0, (size_t)out_size * sizeof(float), stream);

    for (int b0 = 0; b0 < 4; b0 += nb) {
        hipMemsetAsync(xt_hi, 0, xtb, stream);   // zero halo (and interior, overwritten)
        hipMemsetAsync(xt_lo, 0, xtb, stream);
        dim3 tg(6, 384, nb);
        transpose_split<<<tg, 256, 0, stream>>>(x, xt_hi, xt_lo, b0);
        dim3 cg(3, 1152, nb);
        conv_mfma<<<cg, 256, 0, stream>>>(A_hi, A_lo, xt_hi, xt_lo, y_hi, y_lo);
        dim3 rg(8, 18, nb);
        corr_mfma<<<rg, 256, 0, stream>>>(y_hi, y_lo, out, b0);
    }
    softmax_rows<<<1024, 256, 0, stream>>>(out);
}